// Round 14
// baseline (31.327 us; speedup 1.0000x reference)
//
#include <hip/hip_runtime.h>
#include <math.h>

#define NA 512
#define NQC 8

#define NCf ((float)(90.4756 / 6.28318530717958647692))
#define A_ERF 0.70710678118654752f      // 1/sqrt(2)
#define G_COEF 0.79788456080286536f     // sqrt(2/pi)

// ---------------- single dispatch: main + last-block pot reduction ----------------
// grid = 512 blocks (receiver j), block = 512 threads = 8 waves.
// R13 body (wave-private LDS coefficient table, H/G accumulator split,
// contiguous moment loads iq = k*512 + tid). Pot total: each block stores
// potpart[j], release-fences, bumps a counter; the last block re-fences and
// sums all 512 partials in the SAME fixed order pot_kernel used -> bitwise-
// identical result, one dispatch fewer (~3 us).
__global__ __launch_bounds__(512)
void main_kernel(const float* __restrict__ qarr,
                 const float* __restrict__ rarr,
                 const float* __restrict__ uarr,
                 const float* __restrict__ quadarr,
                 const float* __restrict__ kaparr,
                 const float* __restrict__ alparr,
                 float* __restrict__ out,
                 float* __restrict__ potpart,
                 unsigned int* __restrict__ counter) {
    const int j    = blockIdx.x;
    const int tid  = threadIdx.x;
    const int qch  = tid & 7;
    const int lane = tid & 63;
    const int wv   = tid >> 6;     // 8 waves

    __shared__ float sCo[8][64][8];   // 16 KB wave-private coefficient tables

    const float rjx = rarr[j*3+0], rjy = rarr[j*3+1], rjz = rarr[j*3+2];

    const int jq = j * NQC + qch;
    const float* Qj = quadarr + (size_t)jq * 9;
    const float jxx = Qj[0], jyy = Qj[4], jzz = Qj[8];
    const float jxy = 0.5f*(Qj[1]+Qj[3]);
    const float jxz = 0.5f*(Qj[2]+Qj[6]);
    const float jyz = 0.5f*(Qj[5]+Qj[7]);
    const float jtq = jxx + jyy + jzz;

    // ---- coefficient pass: one pair per lane (covers all 8 k-iters) ----
    {
        const int myi = ((lane >> 3) << 6) + (wv << 3) + (lane & 7);
        const float mdx = rjx - rarr[myi*3+0];
        const float mdy = rjy - rarr[myi*3+1];
        const float mdz = rjz - rarr[myi*3+2];
        float r2 = mdx*mdx + mdy*mdy + mdz*mdz;
        const bool diag = (myi == j);
        if (diag) r2 = 1.0f;
        const float ir  = rsqrtf(r2);
        const float rr  = r2 * ir;
        // branch-free erf(rr/sqrt(2)) — A&S 7.1.26, exp shared with G
        const float x   = A_ERF * rr;
        const float E2  = __expf(-0.5f * r2);  // == exp(-x*x)
        const float G   = G_COEF * E2;
        const float t   = __builtin_amdgcn_rcpf(fmaf(0.3275911f, x, 1.0f));
        const float pol = t*(0.254829592f + t*(-0.284496736f + t*(1.421413741f
                         + t*(-1.453152027f + t*1.061405429f))));
        const float E   = fmaf(-pol, E2, 1.0f);
        const float ir2 = ir * ir;
        const float ir4 = ir2 * ir2;
        const float g   = E * ir;
        const float GmG = G - g;
        const float nco = diag ? 0.0f : NCf;
        float4* slot = (float4*)&sCo[wv][lane][0];
        slot[0] = make_float4(nco * g,
                              nco * ir2 * GmG,
                              nco * ir2 * (-3.0f*ir2*GmG - G),
                              nco * ir2 * (15.0f*ir4*GmG + 5.0f*G*ir2 + G));
        slot[1] = make_float4(nco * ir2 * (-105.0f*ir4*ir2*GmG - 35.0f*G*ir4
                                           - 7.0f*G*ir2 - G),
                              mdx, mdy, mdz);
    }
    // no __syncthreads: table is wave-private (writer wave == reader wave)

    float e0 = 0.f, eph = 0.f;
    float Gx = 0.f, Gy = 0.f, Gz = 0.f;   // G = F - H
    float Hx = 0.f, Hy = 0.f, Hz = 0.f;
    float pQQ = 0.f;

    #pragma unroll 4
    for (int k = 0; k < 8; ++k) {
        const int iq = k * 512 + tid;             // == i*NQC + qch (contiguous)
        const int p  = (k << 3) + (lane >> 3);    // pair slot in wave table

        const float4 ca = *(const float4*)&sCo[wv][p][0];
        const float4 cb = *(const float4*)&sCo[wv][p][4];
        const float c0 = ca.x, c1 = ca.y, c2 = ca.z, c3 = ca.w;
        const float c4 = cb.x, dx = cb.y, dy = cb.z, dz = cb.w;

        const float qi = qarr[iq];
        const float ux = uarr[iq*3+0], uy = uarr[iq*3+1], uz = uarr[iq*3+2];
        const float* Qi = quadarr + (size_t)iq * 9;
        const float xx = Qi[0], yy = Qi[4], zz = Qi[8];
        const float xy = 0.5f*(Qi[1]+Qi[3]);
        const float xz = 0.5f*(Qi[2]+Qi[6]);
        const float yz = 0.5f*(Qi[5]+Qi[7]);
        const float tqi = xx + yy + zz;

        const float ud  = ux*dx + uy*dy + uz*dz;
        const float Pdx = xx*dx + xy*dy + xz*dz;
        const float Pdy = xy*dx + yy*dy + yz*dz;
        const float Pdz = xz*dx + yz*dy + zz*dz;
        const float Pdd = Pdx*dx + Pdy*dy + Pdz*dz;

        const float t0 = c0 * qi;
        e0  += t0;
        eph += t0 - c1*ud + 0.5f*(c2*Pdd + c1*tqi);

        const float c1h = 0.5f * c1;
        const float cH = 0.5f*(c2*(ud - tqi) - c3*Pdd);
        const float gf = 0.5f*c2*ud - c1*qi;      // cF - cH
        Hx += cH*dx + c1h*ux - c2*Pdx;
        Hy += cH*dy + c1h*uy - c2*Pdy;
        Hz += cH*dz + c1h*uz - c2*Pdz;
        Gx += gf*dx + c1h*ux;
        Gy += gf*dy + c1h*uy;
        Gz += gf*dz + c1h*uz;

        const float Rdx = jxx*dx + jxy*dy + jxz*dz;
        const float Rdy = jxy*dx + jyy*dy + jyz*dz;
        const float Rdz = jxz*dx + jyz*dy + jzz*dz;
        const float Rdd = Rdx*dx + Rdy*dy + Rdz*dz;
        const float dPR = Pdx*Rdx + Pdy*Rdy + Pdz*Rdz;
        const float frob = xx*jxx + yy*jyy + zz*jzz + 2.0f*(xy*jxy + xz*jxz + yz*jyz);
        pQQ += c4*(Pdd*Rdd)
             + c3*(jtq*Pdd + tqi*Rdd + 4.0f*dPR)
             + c2*(tqi*jtq + 2.0f*frob);
    }

    // recover F = H + G
    const float Fx = Hx + Gx, Fy = Hy + Gy, Fz = Hz + Gz;

    // ---- reduction: segs within wave (offsets 8,16,32), then cross-wave LDS ----
    float acc[9] = {e0, eph, Fx, Fy, Fz, Hx, Hy, Hz, pQQ};
    #pragma unroll
    for (int off = 8; off < 64; off <<= 1) {
        #pragma unroll
        for (int c = 0; c < 9; ++c) acc[c] += __shfl_xor(acc[c], off, 64);
    }
    __shared__ float red[8][8][9];
    if ((lane & 56) == 0) {
        #pragma unroll
        for (int c = 0; c < 9; ++c) red[wv][lane][c] = acc[c];
    }
    __syncthreads();
    if (tid < 8) {
        float v[9];
        #pragma unroll
        for (int c = 0; c < 9; ++c) {
            float s = 0.f;
            #pragma unroll
            for (int w = 0; w < 8; ++w) s += red[w][tid][c];
            v[c] = s;
        }
        const float te0 = v[0], teph = v[1];
        const float tFx = v[2], tFy = v[3], tFz = v[4];
        const float tHx = v[5], tHy = v[6], tHz = v[7];
        const float tQQ = v[8] * 0.125f;
        const int myjq = j * NQC + tid;
        const float qj  = qarr[myjq];
        const float ujx = uarr[myjq*3+0], ujy = uarr[myjq*3+1], ujz = uarr[myjq*3+2];
        const float kapv = kaparr[myjq];
        const float alpv = alparr[myjq];

        float pot = qj * (teph - 0.5f*te0)
                  - (ujx*tHx + ujy*tHy + ujz*tHz)
                  + tQQ
                  - 0.5f * kapv * teph * teph
                  - 0.5f * alpv * (tFx*tFx + tFy*tFy + tFz*tFz);

        out[1 + myjq] = -kapv * teph;
        out[1 + NA*NQC + myjq*3 + 0] = alpv * tFx;
        out[1 + NA*NQC + myjq*3 + 1] = alpv * tFy;
        out[1 + NA*NQC + myjq*3 + 2] = alpv * tFz;

        #pragma unroll
        for (int off = 4; off; off >>= 1) pot += __shfl_xor(pot, off, 8);
        if (tid == 0) potpart[j] = pot;
    }

    // ---- last block sums pot partials (fixed order -> deterministic) ----
    __shared__ unsigned int s_old;
    if (tid == 0) {
        __threadfence();                       // release: potpart[j] visible
        s_old = atomicAdd(counter, 1u);        // device-scope RMW
    }
    __syncthreads();
    if (s_old == NA - 1) {
        __threadfence();                       // acquire side
        if (tid < 64) {
            float s = 0.f;
            #pragma unroll
            for (int m = 0; m < 8; ++m)
                s += __hip_atomic_load(&potpart[tid + m*64],
                                       __ATOMIC_RELAXED, __HIP_MEMORY_SCOPE_AGENT);
            #pragma unroll
            for (int off = 32; off; off >>= 1) s += __shfl_xor(s, off, 64);
            if (tid == 0) out[0] = s;
        }
    }
}

extern "C" void kernel_launch(void* const* d_in, const int* in_sizes, int n_in,
                              void* d_out, int out_size, void* d_ws, size_t ws_size,
                              hipStream_t stream) {
    const float* q    = (const float*)d_in[0];
    const float* r    = (const float*)d_in[1];
    const float* u    = (const float*)d_in[4];
    const float* quad = (const float*)d_in[5];
    const float* kap  = (const float*)d_in[6];
    const float* alp  = (const float*)d_in[7];
    float* out = (float*)d_out;
    float* potpart = (float*)d_ws;                      // 512 floats
    unsigned int* counter = (unsigned int*)((float*)d_ws + NA);
    (void)ws_size; (void)in_sizes; (void)n_in; (void)out_size;

    hipMemsetAsync(counter, 0, sizeof(unsigned int), stream);   // reset arrival counter
    main_kernel<<<NA, 512, 0, stream>>>(q, r, u, quad, kap, alp, out, potpart, counter);
}

// Round 15
// 15.766 us; speedup vs baseline: 1.9871x; 1.9871x over previous
//
#include <hip/hip_runtime.h>
#include <math.h>

#define NA 512
#define NQC 8

#define NCf ((float)(90.4756 / 6.28318530717958647692))
#define A_ERF 0.70710678118654752f      // 1/sqrt(2)
#define G_COEF 0.79788456080286536f     // sqrt(2/pi)

typedef float v2f __attribute__((ext_vector_type(2)));

// ---------------- main kernel ----------------
// grid = 512 blocks (receiver j), block = 512 threads = 8 waves.
// R13 structure (wave-private LDS coefficient table, contiguous moment loads)
// with the k-loop processed TWO iterations at a time in packed fp32
// (ext_vector_type(2) -> v_pk_fma_f32 on CDNA): .x = iter k, .y = iter k+1.
// Halves VALU instruction count in the issue-bound loop if packing holds.
__global__ __launch_bounds__(512)
void main_kernel(const float* __restrict__ qarr,
                 const float* __restrict__ rarr,
                 const float* __restrict__ uarr,
                 const float* __restrict__ quadarr,
                 const float* __restrict__ kaparr,
                 const float* __restrict__ alparr,
                 float* __restrict__ out,
                 float* __restrict__ potpart) {
    const int j    = blockIdx.x;
    const int tid  = threadIdx.x;
    const int qch  = tid & 7;
    const int lane = tid & 63;
    const int wv   = tid >> 6;     // 8 waves

    __shared__ float sCo[8][64][8];   // 16 KB wave-private coefficient tables

    const float rjx = rarr[j*3+0], rjy = rarr[j*3+1], rjz = rarr[j*3+2];

    const int jq = j * NQC + qch;
    const float* Qj = quadarr + (size_t)jq * 9;
    const float jxx = Qj[0], jyy = Qj[4], jzz = Qj[8];
    const float jxy = 0.5f*(Qj[1]+Qj[3]);
    const float jxz = 0.5f*(Qj[2]+Qj[6]);
    const float jyz = 0.5f*(Qj[5]+Qj[7]);
    const float jtq = jxx + jyy + jzz;

    // ---- coefficient pass: one pair per lane (covers all 8 k-iters) ----
    {
        const int myi = ((lane >> 3) << 6) + (wv << 3) + (lane & 7);
        const float mdx = rjx - rarr[myi*3+0];
        const float mdy = rjy - rarr[myi*3+1];
        const float mdz = rjz - rarr[myi*3+2];
        float r2 = mdx*mdx + mdy*mdy + mdz*mdz;
        const bool diag = (myi == j);
        if (diag) r2 = 1.0f;
        const float ir  = rsqrtf(r2);
        const float rr  = r2 * ir;
        // branch-free erf(rr/sqrt(2)) — A&S 7.1.26, exp shared with G
        const float x   = A_ERF * rr;
        const float E2  = __expf(-0.5f * r2);  // == exp(-x*x)
        const float G   = G_COEF * E2;
        const float t   = __builtin_amdgcn_rcpf(fmaf(0.3275911f, x, 1.0f));
        const float pol = t*(0.254829592f + t*(-0.284496736f + t*(1.421413741f
                         + t*(-1.453152027f + t*1.061405429f))));
        const float E   = fmaf(-pol, E2, 1.0f);
        const float ir2 = ir * ir;
        const float ir4 = ir2 * ir2;
        const float g   = E * ir;
        const float GmG = G - g;
        const float nco = diag ? 0.0f : NCf;
        float4* slot = (float4*)&sCo[wv][lane][0];
        slot[0] = make_float4(nco * g,
                              nco * ir2 * GmG,
                              nco * ir2 * (-3.0f*ir2*GmG - G),
                              nco * ir2 * (15.0f*ir4*GmG + 5.0f*G*ir2 + G));
        slot[1] = make_float4(nco * ir2 * (-105.0f*ir4*ir2*GmG - 35.0f*G*ir4
                                           - 7.0f*G*ir2 - G),
                              mdx, mdy, mdz);
    }
    // no __syncthreads: table is wave-private (writer wave == reader wave)

    v2f e0 = 0.f, eph = 0.f;
    v2f Gx = 0.f, Gy = 0.f, Gz = 0.f;   // G = F - H
    v2f Hx = 0.f, Hy = 0.f, Hz = 0.f;
    v2f pQQ = 0.f;

    #pragma unroll
    for (int k2 = 0; k2 < 4; ++k2) {
        const int iq0 = (2*k2) * 512 + tid;       // records this thread consumes
        const int iq1 = iq0 + 512;
        const int p0  = ((2*k2) << 3) + (lane >> 3);
        const int p1  = p0 + 8;

        const float4 ca0 = *(const float4*)&sCo[wv][p0][0];
        const float4 cb0 = *(const float4*)&sCo[wv][p0][4];
        const float4 ca1 = *(const float4*)&sCo[wv][p1][0];
        const float4 cb1 = *(const float4*)&sCo[wv][p1][4];
        const v2f c0 = {ca0.x, ca1.x}, c1 = {ca0.y, ca1.y};
        const v2f c2 = {ca0.z, ca1.z}, c3 = {ca0.w, ca1.w};
        const v2f c4 = {cb0.x, cb1.x};
        const v2f dx = {cb0.y, cb1.y}, dy = {cb0.z, cb1.z}, dz = {cb0.w, cb1.w};

        const v2f qi = {qarr[iq0], qarr[iq1]};
        const v2f ux = {uarr[iq0*3+0], uarr[iq1*3+0]};
        const v2f uy = {uarr[iq0*3+1], uarr[iq1*3+1]};
        const v2f uz = {uarr[iq0*3+2], uarr[iq1*3+2]};
        const float* Qi0 = quadarr + (size_t)iq0 * 9;
        const float* Qi1 = quadarr + (size_t)iq1 * 9;
        const v2f xx = {Qi0[0], Qi1[0]};
        const v2f yy = {Qi0[4], Qi1[4]};
        const v2f zz = {Qi0[8], Qi1[8]};
        const v2f q01 = {Qi0[1], Qi1[1]}, q03 = {Qi0[3], Qi1[3]};
        const v2f q02 = {Qi0[2], Qi1[2]}, q06 = {Qi0[6], Qi1[6]};
        const v2f q05 = {Qi0[5], Qi1[5]}, q07 = {Qi0[7], Qi1[7]};
        const v2f xy = 0.5f*(q01 + q03);
        const v2f xz = 0.5f*(q02 + q06);
        const v2f yz = 0.5f*(q05 + q07);
        const v2f tqi = xx + yy + zz;

        const v2f ud  = ux*dx + uy*dy + uz*dz;
        const v2f Pdx = xx*dx + xy*dy + xz*dz;
        const v2f Pdy = xy*dx + yy*dy + yz*dz;
        const v2f Pdz = xz*dx + yz*dy + zz*dz;
        const v2f Pdd = Pdx*dx + Pdy*dy + Pdz*dz;

        const v2f t0 = c0 * qi;
        e0  += t0;
        eph += t0 - c1*ud + 0.5f*(c2*Pdd + c1*tqi);

        const v2f c1h = 0.5f * c1;
        const v2f cH = 0.5f*(c2*(ud - tqi) - c3*Pdd);
        const v2f gf = 0.5f*c2*ud - c1*qi;      // cF - cH
        Hx += cH*dx + c1h*ux - c2*Pdx;
        Hy += cH*dy + c1h*uy - c2*Pdy;
        Hz += cH*dz + c1h*uz - c2*Pdz;
        Gx += gf*dx + c1h*ux;
        Gy += gf*dy + c1h*uy;
        Gz += gf*dz + c1h*uz;

        const v2f Rdx = jxx*dx + jxy*dy + jxz*dz;
        const v2f Rdy = jxy*dx + jyy*dy + jyz*dz;
        const v2f Rdz = jxz*dx + jyz*dy + jzz*dz;
        const v2f Rdd = Rdx*dx + Rdy*dy + Rdz*dz;
        const v2f dPR = Pdx*Rdx + Pdy*Rdy + Pdz*Rdz;
        const v2f frob = xx*jxx + yy*jyy + zz*jzz + 2.0f*(xy*jxy + xz*jxz + yz*jyz);
        pQQ += c4*(Pdd*Rdd)
             + c3*(jtq*Pdd + tqi*Rdd + 4.0f*dPR)
             + c2*(tqi*jtq + 2.0f*frob);
    }

    // collapse packed lanes; recover F = H + G
    const float e0s = e0.x + e0.y, ephs = eph.x + eph.y;
    const float Hxs = Hx.x + Hx.y, Hys = Hy.x + Hy.y, Hzs = Hz.x + Hz.y;
    const float Fxs = Hxs + Gx.x + Gx.y;
    const float Fys = Hys + Gy.x + Gy.y;
    const float Fzs = Hzs + Gz.x + Gz.y;
    const float pQQs = pQQ.x + pQQ.y;

    // ---- reduction: segs within wave (offsets 8,16,32), then cross-wave LDS ----
    float acc[9] = {e0s, ephs, Fxs, Fys, Fzs, Hxs, Hys, Hzs, pQQs};
    #pragma unroll
    for (int off = 8; off < 64; off <<= 1) {
        #pragma unroll
        for (int c = 0; c < 9; ++c) acc[c] += __shfl_xor(acc[c], off, 64);
    }
    __shared__ float red[8][8][9];
    if ((lane & 56) == 0) {
        #pragma unroll
        for (int c = 0; c < 9; ++c) red[wv][lane][c] = acc[c];
    }
    __syncthreads();
    if (tid < 8) {
        float v[9];
        #pragma unroll
        for (int c = 0; c < 9; ++c) {
            float s = 0.f;
            #pragma unroll
            for (int w = 0; w < 8; ++w) s += red[w][tid][c];
            v[c] = s;
        }
        const float te0 = v[0], teph = v[1];
        const float tFx = v[2], tFy = v[3], tFz = v[4];
        const float tHx = v[5], tHy = v[6], tHz = v[7];
        const float tQQ = v[8] * 0.125f;
        const int myjq = j * NQC + tid;
        const float qj  = qarr[myjq];
        const float ujx = uarr[myjq*3+0], ujy = uarr[myjq*3+1], ujz = uarr[myjq*3+2];
        const float kapv = kaparr[myjq];
        const float alpv = alparr[myjq];

        float pot = qj * (teph - 0.5f*te0)
                  - (ujx*tHx + ujy*tHy + ujz*tHz)
                  + tQQ
                  - 0.5f * kapv * teph * teph
                  - 0.5f * alpv * (tFx*tFx + tFy*tFy + tFz*tFz);

        out[1 + myjq] = -kapv * teph;
        out[1 + NA*NQC + myjq*3 + 0] = alpv * tFx;
        out[1 + NA*NQC + myjq*3 + 1] = alpv * tFy;
        out[1 + NA*NQC + myjq*3 + 2] = alpv * tFz;

        // per-block pot partial -> plain store (no same-address atomic tail)
        #pragma unroll
        for (int off = 4; off; off >>= 1) pot += __shfl_xor(pot, off, 8);
        if (tid == 0) potpart[j] = pot;
    }
}

// ---------------- pot reduction (deterministic, 1 wave) ----------------
__global__ void pot_kernel(const float* __restrict__ potpart, float* __restrict__ out) {
    const int t = threadIdx.x;    // 64 threads
    float s = 0.f;
    #pragma unroll
    for (int m = 0; m < 8; ++m) s += potpart[t + m*64];
    #pragma unroll
    for (int off = 32; off; off >>= 1) s += __shfl_xor(s, off, 64);
    if (t == 0) out[0] = s;
}

extern "C" void kernel_launch(void* const* d_in, const int* in_sizes, int n_in,
                              void* d_out, int out_size, void* d_ws, size_t ws_size,
                              hipStream_t stream) {
    const float* q    = (const float*)d_in[0];
    const float* r    = (const float*)d_in[1];
    const float* u    = (const float*)d_in[4];
    const float* quad = (const float*)d_in[5];
    const float* kap  = (const float*)d_in[6];
    const float* alp  = (const float*)d_in[7];
    float* out = (float*)d_out;
    float* potpart = (float*)d_ws;   // 512 floats
    (void)ws_size; (void)in_sizes; (void)n_in; (void)out_size;

    main_kernel<<<NA, 512, 0, stream>>>(q, r, u, quad, kap, alp, out, potpart);
    pot_kernel<<<1, 64, 0, stream>>>(potpart, out);
}